// Round 12
// baseline (185.631 us; speedup 1.0000x reference)
//
#include <hip/hip_runtime.h>
#include <math.h>

typedef short short8 __attribute__((ext_vector_type(8)));
typedef float f32x4 __attribute__((ext_vector_type(4)));
typedef float f32x16 __attribute__((ext_vector_type(16)));

#define GLB_CP(p) ((const __attribute__((address_space(1))) void*)(p))
#define LDS_CP(p) ((__attribute__((address_space(3))) void*)(p))

__device__ __forceinline__ float2 cmul(float2 a, float2 b) {
    return make_float2(a.x * b.x - a.y * b.y, a.x * b.y + a.y * b.x);
}

__device__ __forceinline__ ushort f2bf(float f) {
    uint u = __float_as_uint(f);
    uint r = (u + 0x7FFFu + ((u >> 16) & 1u)) >> 16;
    return (ushort)r;
}

// ---- prep: conv2 weights -> wt2[tap][icg][oc][ic8] bf16 ; fc1 weights -> bf16 ----
__global__ __launch_bounds__(256) void prep_kernel(
    const float* __restrict__ c2w, const float* __restrict__ f1w,
    ushort* __restrict__ wt2, ushort* __restrict__ wf1)
{
    int i = blockIdx.x * 256 + threadIdx.x;
    if (i < 18432) {
        int icl = i & 7;
        int t = i >> 3;
        int oc = t & 63;
        int t2 = t >> 6;
        int icg = t2 & 3;
        int tap = t2 >> 2;
        int ic = icg * 8 + icl;
        wt2[i] = f2bf(c2w[(oc * 32 + ic) * 9 + tap]);
    } else if (i < 18432 + 1179648) {
        int j = i - 18432;
        wf1[j] = f2bf(f1w[j]);
    }
}

// ---- conv1 + relu -> h1b[b][icg][pix][ic8] bf16 (fully parallel, r3-proven) ----
__global__ __launch_bounds__(256) void conv1_kernel(
    const float* __restrict__ x, const float* __restrict__ w1,
    const float* __restrict__ b1, ushort* __restrict__ h1b)
{
    __shared__ float wl[288];
    __shared__ float bl[32];
    int tid = threadIdx.x;
    for (int e = tid; e < 288; e += 256) wl[e] = w1[e];
    if (tid < 32) bl[tid] = b1[tid];
    __syncthreads();
    int e = blockIdx.x * 256 + tid;          // 2048*676*4 total, exact grid
    int icg = e & 3;
    int t = e >> 2;
    int pix = t % 676;
    int b = t / 676;
    int y = pix / 26, xc = pix % 26;
    const float* xp = x + b * 784 + y * 28 + xc;
    float in9[9];
#pragma unroll
    for (int ky = 0; ky < 3; ++ky)
#pragma unroll
        for (int kx = 0; kx < 3; ++kx) in9[ky * 3 + kx] = xp[ky * 28 + kx];
    short8 outv;
#pragma unroll
    for (int o = 0; o < 8; ++o) {
        int oc = icg * 8 + o;
        float acc = bl[oc];
#pragma unroll
        for (int k = 0; k < 9; ++k) acc = fmaf(in9[k], wl[oc * 9 + k], acc);
        outv[o] = (short)f2bf(fmaxf(acc, 0.f));
    }
    *(short8*)&h1b[((b * 4 + icg) * 676 + pix) * 8] = outv;
}

// ---- conv2 persistent: 256 blocks x 8 images; weights once; full-image dbuf ----
#define EPILOG(ACC0, ACC1, RX, RY)                                                         \
    {                                                                                      \
        int pcolb = (RX) * 4 + 2 * hi;                                                     \
        _Pragma("unroll")                                                                  \
        for (int q = 0; q < 2; ++q) {                                                      \
            int prow = (RY) * 2 + q;                                                       \
            int bs = 8 * q;                                                                \
            float m00 = fmaxf(fmaxf(ACC0[bs], ACC0[bs + 1]), fmaxf(ACC0[bs + 4], ACC0[bs + 5])); \
            float m01 = fmaxf(fmaxf(ACC0[bs + 2], ACC0[bs + 3]), fmaxf(ACC0[bs + 6], ACC0[bs + 7])); \
            uint pk0 = (uint)f2bf(fmaxf(m00 + bias0, 0.f)) | ((uint)f2bf(fmaxf(m01 + bias0, 0.f)) << 16); \
            *(uint*)&pout[lo * 144 + prow * 12 + pcolb] = pk0;                             \
            float m10 = fmaxf(fmaxf(ACC1[bs], ACC1[bs + 1]), fmaxf(ACC1[bs + 4], ACC1[bs + 5])); \
            float m11 = fmaxf(fmaxf(ACC1[bs + 2], ACC1[bs + 3]), fmaxf(ACC1[bs + 6], ACC1[bs + 7])); \
            uint pk1 = (uint)f2bf(fmaxf(m10 + bias1, 0.f)) | ((uint)f2bf(fmaxf(m11 + bias1, 0.f)) << 16); \
            *(uint*)&pout[(lo + 32) * 144 + prow * 12 + pcolb] = pk1;                      \
        }                                                                                  \
    }

__global__ __launch_bounds__(384, 2) void conv2_persist(
    const ushort* __restrict__ h1b, const ushort* __restrict__ wt2,
    const float* __restrict__ c2b, ushort* __restrict__ pooled)
{
    __shared__ __attribute__((aligned(16))) ushort wt_lds[18432];     // [tap9][icg4][oc64][ic8]
    __shared__ __attribute__((aligned(16))) ushort in_lds[2][22016];  // [icg4][pix676][ic8] + pad
    int cu = blockIdx.x;              // 0..255, 8 images each
    int tid = threadIdx.x;
    int wave = tid >> 6;
    int lane = tid & 63;
    int lo = lane & 31;
    int hi = lane >> 5;

    for (int c = wave; c < 36; c += 6) {
        const ushort* src = wt2 + (size_t)(c * 64 + lane) * 8;
        __builtin_amdgcn_global_load_lds(GLB_CP(src), LDS_CP(wt_lds + c * 512), 16, 0, 0);
    }
    {
        const ushort* base = h1b + (size_t)(cu * 8) * 21632;
        for (int c = wave; c < 43; c += 6) {
            int e = c * 64 + lane;
            if (e > 2703) e = 2703;
            __builtin_amdgcn_global_load_lds(GLB_CP(base + (size_t)e * 8),
                                             LDS_CP(in_lds[0] + c * 512), 16, 0, 0);
        }
    }
    float bias0 = c2b[lo];
    float bias1 = c2b[lo + 32];
    __syncthreads();

    int pb[3];
#pragma unroll
    for (int i = 0; i < 3; ++i) {
        int r = wave + 6 * i;
        int rx = r % 3, ry = r / 3;
        int xcoord = rx * 8 + (lo & 7);
        int ycoord = ry * 4 + (lo >> 3);
        pb[i] = ycoord * 26 + xcoord;
    }
    int rx0 = wave % 3, ry0 = wave / 3;
    int rx1 = (wave + 6) % 3, ry1 = (wave + 6) / 3;
    int rx2 = (wave + 12) % 3, ry2 = (wave + 12) / 3;

    for (int j = 0; j < 8; ++j) {
        if (j < 7) {
            const ushort* base = h1b + (size_t)(cu * 8 + j + 1) * 21632;
            ushort* dst = in_lds[(j + 1) & 1];
            for (int c = wave; c < 43; c += 6) {
                int e = c * 64 + lane;
                if (e > 2703) e = 2703;
                __builtin_amdgcn_global_load_lds(GLB_CP(base + (size_t)e * 8),
                                                 LDS_CP(dst + c * 512), 16, 0, 0);
            }
        }

        const ushort* ib = in_lds[j & 1];
        f32x16 aA0 = (f32x16)0.f, aA1 = (f32x16)0.f;
        f32x16 aB0 = (f32x16)0.f, aB1 = (f32x16)0.f;
        f32x16 aC0 = (f32x16)0.f, aC1 = (f32x16)0.f;

#pragma unroll
        for (int tap = 0; tap < 9; ++tap) {
            int off = (tap / 3) * 26 + (tap % 3);
#pragma unroll
            for (int ks = 0; ks < 2; ++ks) {
                const ushort* wp = &wt_lds[((tap * 4 + ks * 2 + hi) * 64) * 8];
                short8 a0 = *(const short8*)(wp + lo * 8);
                short8 a1 = *(const short8*)(wp + (32 + lo) * 8);
                const ushort* ip = &ib[((ks * 2 + hi) * 676 + off) * 8];
                short8 b0 = *(const short8*)(ip + pb[0] * 8);
                short8 b1 = *(const short8*)(ip + pb[1] * 8);
                short8 b2 = *(const short8*)(ip + pb[2] * 8);
                aA0 = __builtin_amdgcn_mfma_f32_32x32x16_bf16(b0, a0, aA0, 0, 0, 0);
                aA1 = __builtin_amdgcn_mfma_f32_32x32x16_bf16(b0, a1, aA1, 0, 0, 0);
                aB0 = __builtin_amdgcn_mfma_f32_32x32x16_bf16(b1, a0, aB0, 0, 0, 0);
                aB1 = __builtin_amdgcn_mfma_f32_32x32x16_bf16(b1, a1, aB1, 0, 0, 0);
                aC0 = __builtin_amdgcn_mfma_f32_32x32x16_bf16(b2, a0, aC0, 0, 0, 0);
                aC1 = __builtin_amdgcn_mfma_f32_32x32x16_bf16(b2, a1, aC1, 0, 0, 0);
            }
        }

        ushort* pout = pooled + (size_t)(cu * 8 + j) * 9216;
        EPILOG(aA0, aA1, rx0, ry0)
        EPILOG(aB0, aB1, rx1, ry1)
        EPILOG(aC0, aC1, rx2, ry2)
        __syncthreads();
    }
}

// ---- fc1 MFMA: pooled[2048,9216]bf16 x wf1[128,9216]bf16^T, 4-way K-split ----
__global__ __launch_bounds__(256) void fc1_mfma(
    const ushort* __restrict__ pooled, const ushort* __restrict__ wf1,
    float* __restrict__ part)
{
    int bx = blockIdx.x, by = blockIdx.y;
    int tid = threadIdx.x;
    int wid = tid >> 6, lane = tid & 63;
    int lo = lane & 15, hi = lane >> 4;
    int m0 = bx * 32;
    int kb = by * 2304;

    f32x4 acc[2][2];
#pragma unroll
    for (int mt = 0; mt < 2; ++mt)
#pragma unroll
        for (int j = 0; j < 2; ++j) acc[mt][j] = (f32x4)0.f;

    const ushort* arow0 = pooled + (size_t)(m0 + lo) * 9216 + kb + hi * 8;
    const ushort* arow1 = arow0 + 16 * 9216;
    const ushort* brow0 = wf1 + (size_t)(wid * 32 + lo) * 9216 + kb + hi * 8;
    const ushort* brow1 = brow0 + 16 * 9216;

    for (int kt = 0; kt < 72; ++kt) {
        short8 a0 = *(const short8*)(arow0 + kt * 32);
        short8 a1 = *(const short8*)(arow1 + kt * 32);
        short8 b0 = *(const short8*)(brow0 + kt * 32);
        short8 b1 = *(const short8*)(brow1 + kt * 32);
        acc[0][0] = __builtin_amdgcn_mfma_f32_16x16x32_bf16(a0, b0, acc[0][0], 0, 0, 0);
        acc[1][0] = __builtin_amdgcn_mfma_f32_16x16x32_bf16(a1, b0, acc[1][0], 0, 0, 0);
        acc[0][1] = __builtin_amdgcn_mfma_f32_16x16x32_bf16(a0, b1, acc[0][1], 0, 0, 0);
        acc[1][1] = __builtin_amdgcn_mfma_f32_16x16x32_bf16(a1, b1, acc[1][1], 0, 0, 0);
    }
    float* pp = part + (size_t)by * 262144;
#pragma unroll
    for (int mt = 0; mt < 2; ++mt)
#pragma unroll
        for (int j = 0; j < 2; ++j)
#pragma unroll
            for (int r = 0; r < 4; ++r)
                pp[(m0 + mt * 16 + hi * 4 + r) * 128 + wid * 32 + j * 16 + lo] = acc[mt][j][r];
}

__global__ __launch_bounds__(256) void fc1_reduce_kernel(
    const float* __restrict__ part, const float* __restrict__ bias,
    float* __restrict__ outp)
{
    int idx = blockIdx.x * 256 + threadIdx.x;   // < 262144
    float s = 0.f;
#pragma unroll
    for (int ks = 0; ks < 4; ++ks) s += part[ks * 262144 + idx];
    outp[idx] = fmaxf(s + bias[idx & 127], 0.f);
}

// ---- qprep: per-item fc2 + all gate-parameter trig (one thread per item) ----
// Emits 64-float param block: [0:40) v[k][0..1] re/im; [40:44) p1,p2;
// [44:52) rotA m00,m01,m10,m11; [52:60) rotB.
__global__ __launch_bounds__(256) void qprep_kernel(
    const float* __restrict__ h, const float* __restrict__ f2w,
    const float* __restrict__ f2b, const float* __restrict__ theta0,
    const float* __restrict__ theta_rz, const float* __restrict__ theta_ps,
    const float* __restrict__ rot_p, float* __restrict__ params)
{
    int item = blockIdx.x * 256 + threadIdx.x;
    if (item >= 2048) return;
    const float* hp = h + (size_t)item * 128;
    float a[10];
#pragma unroll
    for (int n = 0; n < 10; ++n) {
        const float* wp = f2w + n * 128;
        float s = f2b[n];
        for (int k = 0; k < 128; ++k) s = fmaf(hp[k], wp[k], s);
        a[n] = 6.28318530718f / (1.f + expf(-s));
    }
    float th[10];
#pragma unroll
    for (int k = 0; k < 10; ++k) th[k] = theta0[k] + a[k];
    th[1] += a[1];
    th[5] -= 0.78539816339745f;   // RX(-pi/4) on wire 5

    float2 v[10][2];
#pragma unroll
    for (int k = 0; k < 10; ++k) {
        float c, sn; sincosf(0.5f * th[k], &sn, &c);
        v[k][0] = make_float2(c, 0.f);
        v[k][1] = make_float2(0.f, -sn);
    }
    { float c, sn; sincosf(0.5f * a[2], &sn, &c);
      float2 v0 = v[2][0], v1 = v[2][1];
      v[2][0] = make_float2(c * v0.x - sn * v1.x, c * v0.y - sn * v1.y);
      v[2][1] = make_float2(sn * v0.x + c * v1.x, sn * v0.y + c * v1.y); }
    { float c, sn; sincosf(0.5f * a[3], &sn, &c);
      v[3][0] = cmul(v[3][0], make_float2(c, -sn));
      v[3][1] = cmul(v[3][1], make_float2(c, sn)); }
    { float2 t = v[4][1]; v[4][1] = make_float2(-t.y, t.x); }
    { const float r = 0.70710678118655f;
      float2 t = v[5][1]; v[5][1] = make_float2(r * (t.x - t.y), r * (t.x + t.y)); }
    { float c, sn; sincosf(0.5f * theta_rz[0], &sn, &c);
      v[6][0] = cmul(v[6][0], make_float2(c, -sn));
      v[6][1] = cmul(v[6][1], make_float2(c, sn)); }
    { float2 p = v[7][0], q = v[7][1];
      v[7][0] = make_float2(0.5f * ((p.x - p.y) + (q.x + q.y)),
                            0.5f * ((p.x + p.y) + (q.y - q.x)));
      v[7][1] = make_float2(0.5f * ((p.x + p.y) + (q.x - q.y)),
                            0.5f * ((p.y - p.x) + (q.x + q.y))); }

    float P[64];
#pragma unroll
    for (int k = 0; k < 10; ++k) {
        P[k * 4 + 0] = v[k][0].x; P[k * 4 + 1] = v[k][0].y;
        P[k * 4 + 2] = v[k][1].x; P[k * 4 + 3] = v[k][1].y;
    }
    { float c1, s1; sincosf(theta_ps[0], &s1, &c1); P[40] = c1; P[41] = s1; }
    { float c2, s2; sincosf(a[7], &s2, &c2); P[42] = c2; P[43] = s2; }
    { // rotA: phi=rot_p[0], th=rot_p[1], om=rot_p[2]
      float c, sn; sincosf(0.5f * rot_p[1], &sn, &c);
      float A = 0.5f * (rot_p[0] + rot_p[2]), Bv = 0.5f * (rot_p[0] - rot_p[2]);
      float cA, sA; sincosf(A, &sA, &cA);
      float cB, sB; sincosf(Bv, &sB, &cB);
      P[44] = cA * c;  P[45] = -sA * c;
      P[46] = -cB * sn; P[47] = -sB * sn;
      P[48] = cB * sn;  P[49] = -sB * sn;
      P[50] = cA * c;  P[51] = sA * c; }
    { // rotB: phi=a[6], th=a[7], om=a[8]
      float c, sn; sincosf(0.5f * a[7], &sn, &c);
      float A = 0.5f * (a[6] + a[8]), Bv = 0.5f * (a[6] - a[8]);
      float cA, sA; sincosf(A, &sA, &cA);
      float cB, sB; sincosf(Bv, &sB, &cB);
      P[52] = cA * c;  P[53] = -sA * c;
      P[54] = -cB * sn; P[55] = -sB * sn;
      P[56] = cB * sn;  P[57] = -sB * sn;
      P[58] = cA * c;  P[59] = sA * c; }
    P[60] = 0.f; P[61] = 0.f; P[62] = 0.f; P[63] = 0.f;

    float4* dst = (float4*)(params + (size_t)item * 64);
#pragma unroll
    for (int q = 0; q < 16; ++q)
        dst[q] = make_float4(P[q * 4], P[q * 4 + 1], P[q * 4 + 2], P[q * 4 + 3]);
}

// ---------------- quantum circuit (params precomputed) ----------------
__device__ __forceinline__ void apply_rot2(float2* s, int p, float2 m00, float2 m01,
                                           float2 m10, float2 m11, int tid)
{
    for (int q = tid; q < 512; q += 256) {
        int i0 = ((q >> p) << (p + 1)) | (q & ((1 << p) - 1));
        int i1 = i0 | (1 << p);
        float2 aa = s[i0], bb = s[i1];
        s[i0] = make_float2(m00.x * aa.x - m00.y * aa.y + m01.x * bb.x - m01.y * bb.y,
                            m00.x * aa.y + m00.y * aa.x + m01.x * bb.y + m01.y * bb.x);
        s[i1] = make_float2(m10.x * aa.x - m10.y * aa.y + m11.x * bb.x - m11.y * bb.y,
                            m10.x * aa.y + m10.y * aa.x + m11.x * bb.y + m11.y * bb.x);
    }
}

__global__ __launch_bounds__(256) void quantum_kernel(
    const float* __restrict__ params, float* __restrict__ out)
{
    __shared__ float2 s[1024];
    __shared__ float red[40];
    int b = blockIdx.x;
    int tid = threadIdx.x;
    const float* P = params + (size_t)b * 64;

    float2 v[10][2];
#pragma unroll
    for (int k = 0; k < 10; ++k) {
        float4 t = *(const float4*)(P + k * 4);
        v[k][0] = make_float2(t.x, t.y);
        v[k][1] = make_float2(t.z, t.w);
    }

    // product state init — compile-time indices only (no scratch, r9-proven)
    for (int i = tid; i < 1024; i += 256) {
        float2 c = ((i >> 9) & 1) ? v[0][1] : v[0][0];
#pragma unroll
        for (int k = 1; k < 10; ++k) {
            float2 vk = ((i >> (9 - k)) & 1) ? v[k][1] : v[k][0];
            c = cmul(c, vk);
        }
        s[i] = c;
    }
    __syncthreads();

    for (int i = tid; i < 1024; i += 256)
        if (((i >> 9) & 1) && ((i >> 4) & 1)) { s[i].x = -s[i].x; s[i].y = -s[i].y; }
    __syncthreads();
    { int j = tid;
      int i0 = 512 | ((j >> 4) << 5) | (j & 15);
      int i1 = i0 | 16;
      float2 t0 = s[i0], t1 = s[i1];
      s[i0] = t1; s[i1] = t0; }
    __syncthreads();
    { int j = tid;
      int i0 = 512 | ((j >> 4) << 5) | (j & 15);
      int i1 = i0 | 16;
      float2 t0 = s[i0], t1 = s[i1];
      s[i0] = make_float2(t1.y, -t1.x);
      s[i1] = make_float2(-t0.y, t0.x); }
    __syncthreads();
    { int j = tid;
      int i0 = (j & 1) | (((j >> 1) & 15) << 2) | (((j >> 5) & 7) << 7) | 64;
      int i1 = i0 | 2;
      float2 t0 = s[i0], t1 = s[i1];
      s[i0] = make_float2(t1.y, -t1.x);
      s[i1] = make_float2(-t0.y, t0.x); }
    __syncthreads();
    { int j = tid;
      int i0 = (j & 63) | 128 | (((j >> 6) & 3) << 8);
      int i1 = i0 ^ 0xC0;
      float2 t0 = s[i0], t1 = s[i1];
      s[i0] = t1; s[i1] = t0; }
    __syncthreads();
    if (tid < 128) {
      int j = tid;
      int i0 = (j & 7) | 16 | 32 | (((j >> 3) & 15) << 6);
      int i1 = i0 ^ 0x18;
      float2 t0 = s[i0], t1 = s[i1];
      s[i0] = t1; s[i1] = t0; }
    __syncthreads();
    if (tid < 128) {
      int j = tid;
      int i0 = (j & 1) | 2 | (((j >> 1) & 3) << 2) | 16 | (((j >> 3) & 15) << 5);
      int i1 = i0 | 512;
      float2 t0 = s[i0], t1 = s[i1];
      s[i0] = t1; s[i1] = t0; }
    __syncthreads();
    { float2 p1 = make_float2(P[40], P[41]), p2 = make_float2(P[42], P[43]);
      for (int i = tid; i < 1024; i += 256) {
          float2 t = s[i];
          if ((i >> 1) & 1) t = cmul(t, p1);
          if ((i >> 2) & 1) t = cmul(t, p2);
          s[i] = t;
      } }
    __syncthreads();
    apply_rot2(s, 5, make_float2(P[44], P[45]), make_float2(P[46], P[47]),
               make_float2(P[48], P[49]), make_float2(P[50], P[51]), tid);
    __syncthreads();
    apply_rot2(s, 4, make_float2(P[52], P[53]), make_float2(P[54], P[55]),
               make_float2(P[56], P[57]), make_float2(P[58], P[59]), tid);
    __syncthreads();

    int wave = tid >> 6;
    for (int k = 0; k < 10; ++k) {
        int p = 9 - k;
        float part = 0.f;
        for (int q = tid; q < 512; q += 256) {
            int i0 = ((q >> p) << (p + 1)) | (q & ((1 << p) - 1));
            int i1 = i0 | (1 << p);
            float2 aa = s[i0], bb = s[i1];
            part += aa.x * bb.y - aa.y * bb.x;
        }
        part *= 2.f;
#pragma unroll
        for (int off = 32; off > 0; off >>= 1)
            part += __shfl_down(part, off, 64);
        if ((tid & 63) == 0) red[k * 4 + wave] = part;
    }
    __syncthreads();
    if (tid == 0) {
        float ev[10];
        float mx = -1e30f;
#pragma unroll
        for (int k = 0; k < 10; ++k) {
            ev[k] = red[k * 4] + red[k * 4 + 1] + red[k * 4 + 2] + red[k * 4 + 3];
            mx = fmaxf(mx, ev[k]);
        }
        float sum = 0.f;
#pragma unroll
        for (int k = 0; k < 10; ++k) sum += expf(ev[k] - mx);
        float lse = mx + logf(sum);
#pragma unroll
        for (int k = 0; k < 10; ++k) out[b * 10 + k] = ev[k] - lse;
    }
}

extern "C" void kernel_launch(void* const* d_in, const int* in_sizes, int n_in,
                              void* d_out, int out_size, void* d_ws, size_t ws_size,
                              hipStream_t stream)
{
    (void)in_sizes; (void)n_in; (void)out_size; (void)ws_size;
    const float* x    = (const float*)d_in[0];
    const float* c1w  = (const float*)d_in[1];
    const float* c1b  = (const float*)d_in[2];
    const float* c2w  = (const float*)d_in[3];
    const float* c2b  = (const float*)d_in[4];
    const float* f1w  = (const float*)d_in[5];
    const float* f1b  = (const float*)d_in[6];
    const float* f2w  = (const float*)d_in[7];
    const float* f2b  = (const float*)d_in[8];
    const float* th0  = (const float*)d_in[9];
    const float* trz  = (const float*)d_in[10];
    const float* tps  = (const float*)d_in[11];
    const float* rotp = (const float*)d_in[12];
    float* out = (float*)d_out;

    char* ws = (char*)d_ws;
    ushort* h1b    = (ushort*)(ws);                       // 88,604,672 B
    ushort* pooled = (ushort*)(ws + 88604672);            // 37,748,736 B
    ushort* wt2    = (ushort*)(ws + 126353408);           //     36,864 B
    ushort* wf1    = (ushort*)(ws + 126390272);           //  2,359,296 B
    float*  part   = (float*)(ws + 128749568);            //  4,194,304 B
    float*  fc1o   = (float*)(ws + 132943872);            //  1,048,576 B
    float*  params = (float*)(ws + 133992448);            //    524,288 B

    prep_kernel<<<4680, 256, 0, stream>>>(c2w, f1w, wt2, wf1);
    conv1_kernel<<<21632, 256, 0, stream>>>(x, c1w, c1b, h1b);
    conv2_persist<<<256, 384, 0, stream>>>(h1b, wt2, c2b, pooled);
    fc1_mfma<<<dim3(64, 4), 256, 0, stream>>>(pooled, wf1, part);
    fc1_reduce_kernel<<<1024, 256, 0, stream>>>(part, f1b, fc1o);
    qprep_kernel<<<8, 256, 0, stream>>>(fc1o, f2w, f2b, th0, trz, tps, rotp, params);
    quantum_kernel<<<2048, 256, 0, stream>>>(params, out);
}

// Round 13
// 151.208 us; speedup vs baseline: 1.2277x; 1.2277x over previous
//
#include <hip/hip_runtime.h>
#include <math.h>

typedef short short8 __attribute__((ext_vector_type(8)));
typedef float f32x4 __attribute__((ext_vector_type(4)));
typedef float f32x16 __attribute__((ext_vector_type(16)));

#define GLB_CP(p) ((const __attribute__((address_space(1))) void*)(p))
#define LDS_CP(p) ((__attribute__((address_space(3))) void*)(p))

__device__ __forceinline__ float2 cmul(float2 a, float2 b) {
    return make_float2(a.x * b.x - a.y * b.y, a.x * b.y + a.y * b.x);
}

__device__ __forceinline__ ushort f2bf(float f) {
    uint u = __float_as_uint(f);
    uint r = (u + 0x7FFFu + ((u >> 16) & 1u)) >> 16;
    return (ushort)r;
}

// ---- prep: conv2 weights -> wt2[tap][icg][oc][ic8] bf16 ; fc1 weights -> bf16 ----
__global__ __launch_bounds__(256) void prep_kernel(
    const float* __restrict__ c2w, const float* __restrict__ f1w,
    ushort* __restrict__ wt2, ushort* __restrict__ wf1)
{
    int i = blockIdx.x * 256 + threadIdx.x;
    if (i < 18432) {
        int icl = i & 7;
        int t = i >> 3;
        int oc = t & 63;
        int t2 = t >> 6;
        int icg = t2 & 3;
        int tap = t2 >> 2;
        int ic = icg * 8 + icl;
        wt2[i] = f2bf(c2w[(oc * 32 + ic) * 9 + tap]);
    } else if (i < 18432 + 1179648) {
        int j = i - 18432;
        wf1[j] = f2bf(f1w[j]);
    }
}

// ---- conv1 + relu -> h1b[b][icg][pix][ic8] bf16 (fully parallel, r3-proven) ----
__global__ __launch_bounds__(256) void conv1_kernel(
    const float* __restrict__ x, const float* __restrict__ w1,
    const float* __restrict__ b1, ushort* __restrict__ h1b)
{
    __shared__ float wl[288];
    __shared__ float bl[32];
    int tid = threadIdx.x;
    for (int e = tid; e < 288; e += 256) wl[e] = w1[e];
    if (tid < 32) bl[tid] = b1[tid];
    __syncthreads();
    int e = blockIdx.x * 256 + tid;          // 2048*676*4 total, exact grid
    int icg = e & 3;
    int t = e >> 2;
    int pix = t % 676;
    int b = t / 676;
    int y = pix / 26, xc = pix % 26;
    const float* xp = x + b * 784 + y * 28 + xc;
    float in9[9];
#pragma unroll
    for (int ky = 0; ky < 3; ++ky)
#pragma unroll
        for (int kx = 0; kx < 3; ++kx) in9[ky * 3 + kx] = xp[ky * 28 + kx];
    short8 outv;
#pragma unroll
    for (int o = 0; o < 8; ++o) {
        int oc = icg * 8 + o;
        float acc = bl[oc];
#pragma unroll
        for (int k = 0; k < 9; ++k) acc = fmaf(in9[k], wl[oc * 9 + k], acc);
        outv[o] = (short)f2bf(fmaxf(acc, 0.f));
    }
    *(short8*)&h1b[((b * 4 + icg) * 676 + pix) * 8] = outv;
}

// ---- conv2 persistent: 256 blocks x 8 images; weights once; full-image dbuf ----
#define EPILOG(ACC0, ACC1, RX, RY)                                                         \
    {                                                                                      \
        int pcolb = (RX) * 4 + 2 * hi;                                                     \
        _Pragma("unroll")                                                                  \
        for (int q = 0; q < 2; ++q) {                                                      \
            int prow = (RY) * 2 + q;                                                       \
            int bs = 8 * q;                                                                \
            float m00 = fmaxf(fmaxf(ACC0[bs], ACC0[bs + 1]), fmaxf(ACC0[bs + 4], ACC0[bs + 5])); \
            float m01 = fmaxf(fmaxf(ACC0[bs + 2], ACC0[bs + 3]), fmaxf(ACC0[bs + 6], ACC0[bs + 7])); \
            uint pk0 = (uint)f2bf(fmaxf(m00 + bias0, 0.f)) | ((uint)f2bf(fmaxf(m01 + bias0, 0.f)) << 16); \
            *(uint*)&pout[lo * 144 + prow * 12 + pcolb] = pk0;                             \
            float m10 = fmaxf(fmaxf(ACC1[bs], ACC1[bs + 1]), fmaxf(ACC1[bs + 4], ACC1[bs + 5])); \
            float m11 = fmaxf(fmaxf(ACC1[bs + 2], ACC1[bs + 3]), fmaxf(ACC1[bs + 6], ACC1[bs + 7])); \
            uint pk1 = (uint)f2bf(fmaxf(m10 + bias1, 0.f)) | ((uint)f2bf(fmaxf(m11 + bias1, 0.f)) << 16); \
            *(uint*)&pout[(lo + 32) * 144 + prow * 12 + pcolb] = pk1;                      \
        }                                                                                  \
    }

__global__ __launch_bounds__(384, 2) void conv2_persist(
    const ushort* __restrict__ h1b, const ushort* __restrict__ wt2,
    const float* __restrict__ c2b, ushort* __restrict__ pooled)
{
    __shared__ __attribute__((aligned(16))) ushort wt_lds[18432];     // [tap9][icg4][oc64][ic8]
    __shared__ __attribute__((aligned(16))) ushort in_lds[2][22016];  // [icg4][pix676][ic8] + pad
    int cu = blockIdx.x;              // 0..255, 8 images each
    int tid = threadIdx.x;
    int wave = tid >> 6;
    int lane = tid & 63;
    int lo = lane & 31;
    int hi = lane >> 5;

    for (int c = wave; c < 36; c += 6) {
        const ushort* src = wt2 + (size_t)(c * 64 + lane) * 8;
        __builtin_amdgcn_global_load_lds(GLB_CP(src), LDS_CP(wt_lds + c * 512), 16, 0, 0);
    }
    {
        const ushort* base = h1b + (size_t)(cu * 8) * 21632;
        for (int c = wave; c < 43; c += 6) {
            int e = c * 64 + lane;
            if (e > 2703) e = 2703;
            __builtin_amdgcn_global_load_lds(GLB_CP(base + (size_t)e * 8),
                                             LDS_CP(in_lds[0] + c * 512), 16, 0, 0);
        }
    }
    float bias0 = c2b[lo];
    float bias1 = c2b[lo + 32];
    __syncthreads();

    int pb[3];
#pragma unroll
    for (int i = 0; i < 3; ++i) {
        int r = wave + 6 * i;
        int rx = r % 3, ry = r / 3;
        int xcoord = rx * 8 + (lo & 7);
        int ycoord = ry * 4 + (lo >> 3);
        pb[i] = ycoord * 26 + xcoord;
    }
    int rx0 = wave % 3, ry0 = wave / 3;
    int rx1 = (wave + 6) % 3, ry1 = (wave + 6) / 3;
    int rx2 = (wave + 12) % 3, ry2 = (wave + 12) / 3;

    for (int j = 0; j < 8; ++j) {
        if (j < 7) {
            const ushort* base = h1b + (size_t)(cu * 8 + j + 1) * 21632;
            ushort* dst = in_lds[(j + 1) & 1];
            for (int c = wave; c < 43; c += 6) {
                int e = c * 64 + lane;
                if (e > 2703) e = 2703;
                __builtin_amdgcn_global_load_lds(GLB_CP(base + (size_t)e * 8),
                                                 LDS_CP(dst + c * 512), 16, 0, 0);
            }
        }

        const ushort* ib = in_lds[j & 1];
        f32x16 aA0 = (f32x16)0.f, aA1 = (f32x16)0.f;
        f32x16 aB0 = (f32x16)0.f, aB1 = (f32x16)0.f;
        f32x16 aC0 = (f32x16)0.f, aC1 = (f32x16)0.f;

#pragma unroll
        for (int tap = 0; tap < 9; ++tap) {
            int off = (tap / 3) * 26 + (tap % 3);
#pragma unroll
            for (int ks = 0; ks < 2; ++ks) {
                const ushort* wp = &wt_lds[((tap * 4 + ks * 2 + hi) * 64) * 8];
                short8 a0 = *(const short8*)(wp + lo * 8);
                short8 a1 = *(const short8*)(wp + (32 + lo) * 8);
                const ushort* ip = &ib[((ks * 2 + hi) * 676 + off) * 8];
                short8 b0 = *(const short8*)(ip + pb[0] * 8);
                short8 b1 = *(const short8*)(ip + pb[1] * 8);
                short8 b2 = *(const short8*)(ip + pb[2] * 8);
                aA0 = __builtin_amdgcn_mfma_f32_32x32x16_bf16(b0, a0, aA0, 0, 0, 0);
                aA1 = __builtin_amdgcn_mfma_f32_32x32x16_bf16(b0, a1, aA1, 0, 0, 0);
                aB0 = __builtin_amdgcn_mfma_f32_32x32x16_bf16(b1, a0, aB0, 0, 0, 0);
                aB1 = __builtin_amdgcn_mfma_f32_32x32x16_bf16(b1, a1, aB1, 0, 0, 0);
                aC0 = __builtin_amdgcn_mfma_f32_32x32x16_bf16(b2, a0, aC0, 0, 0, 0);
                aC1 = __builtin_amdgcn_mfma_f32_32x32x16_bf16(b2, a1, aC1, 0, 0, 0);
            }
        }

        ushort* pout = pooled + (size_t)(cu * 8 + j) * 9216;
        EPILOG(aA0, aA1, rx0, ry0)
        EPILOG(aB0, aB1, rx1, ry1)
        EPILOG(aC0, aC1, rx2, ry2)
        __syncthreads();
    }
}

// ---- fc1 MFMA: pooled[2048,9216]bf16 x wf1[128,9216]bf16^T, 4-way K-split ----
__global__ __launch_bounds__(256) void fc1_mfma(
    const ushort* __restrict__ pooled, const ushort* __restrict__ wf1,
    float* __restrict__ part)
{
    int bx = blockIdx.x, by = blockIdx.y;
    int tid = threadIdx.x;
    int wid = tid >> 6, lane = tid & 63;
    int lo = lane & 15, hi = lane >> 4;
    int m0 = bx * 32;
    int kb = by * 2304;

    f32x4 acc[2][2];
#pragma unroll
    for (int mt = 0; mt < 2; ++mt)
#pragma unroll
        for (int j = 0; j < 2; ++j) acc[mt][j] = (f32x4)0.f;

    const ushort* arow0 = pooled + (size_t)(m0 + lo) * 9216 + kb + hi * 8;
    const ushort* arow1 = arow0 + 16 * 9216;
    const ushort* brow0 = wf1 + (size_t)(wid * 32 + lo) * 9216 + kb + hi * 8;
    const ushort* brow1 = brow0 + 16 * 9216;

    for (int kt = 0; kt < 72; ++kt) {
        short8 a0 = *(const short8*)(arow0 + kt * 32);
        short8 a1 = *(const short8*)(arow1 + kt * 32);
        short8 b0 = *(const short8*)(brow0 + kt * 32);
        short8 b1 = *(const short8*)(brow1 + kt * 32);
        acc[0][0] = __builtin_amdgcn_mfma_f32_16x16x32_bf16(a0, b0, acc[0][0], 0, 0, 0);
        acc[1][0] = __builtin_amdgcn_mfma_f32_16x16x32_bf16(a1, b0, acc[1][0], 0, 0, 0);
        acc[0][1] = __builtin_amdgcn_mfma_f32_16x16x32_bf16(a0, b1, acc[0][1], 0, 0, 0);
        acc[1][1] = __builtin_amdgcn_mfma_f32_16x16x32_bf16(a1, b1, acc[1][1], 0, 0, 0);
    }
    float* pp = part + (size_t)by * 262144;
#pragma unroll
    for (int mt = 0; mt < 2; ++mt)
#pragma unroll
        for (int j = 0; j < 2; ++j)
#pragma unroll
            for (int r = 0; r < 4; ++r)
                pp[(m0 + mt * 16 + hi * 4 + r) * 128 + wid * 32 + j * 16 + lo] = acc[mt][j][r];
}

__global__ __launch_bounds__(256) void fc1_reduce_kernel(
    const float* __restrict__ part, const float* __restrict__ bias,
    float* __restrict__ outp)
{
    int idx = blockIdx.x * 256 + threadIdx.x;   // < 262144
    float s = 0.f;
#pragma unroll
    for (int ks = 0; ks < 4; ++ks) s += part[ks * 262144 + idx];
    outp[idx] = fmaxf(s + bias[idx & 127], 0.f);
}

// ---- fc2 + sigmoid*2pi -> angles[2048,10] (r11-proven) ----
__global__ __launch_bounds__(256) void fc2_kernel(
    const float* __restrict__ h, const float* __restrict__ w,
    const float* __restrict__ bias, float* __restrict__ ang)
{
    int idx = blockIdx.x * 256 + threadIdx.x;
    if (idx >= 20480) return;
    int b = idx / 10, n = idx % 10;
    const float* hp = h + b * 128;
    const float* wp = w + n * 128;
    float s = bias[n];
    for (int k = 0; k < 128; ++k) s = fmaf(hp[k], wp[k], s);
    ang[idx] = 6.28318530718f / (1.f + expf(-s));
}

// ---------------- quantum circuit (collapsed gate sequence) ----------------
// Algebra: CZ*CNOT*CY on (0,5) == diag(1,1,-i,-i) == phase -i on wire0  [folded into v0]
//          SWAP(2,3) pushed into init (exchange v2/v3 factors); CY(3,8)->CY(2,8)
//          Phase(a7)@wire7 commutes to init [folded into v7]
//          Phase(tps)@wire8 commutes back to the CY(2,8) pass [merged]
// Passes: init | CY28+tps | CSWAP | TOFF | Rot(b5) | Rot(b4) | <Y_k>  (7 barriers vs 12)
__device__ __forceinline__ void apply_rot2(float2* s, int p, float2 m00, float2 m01,
                                           float2 m10, float2 m11, int tid)
{
    for (int q = tid; q < 512; q += 256) {
        int i0 = ((q >> p) << (p + 1)) | (q & ((1 << p) - 1));
        int i1 = i0 | (1 << p);
        float2 aa = s[i0], bb = s[i1];
        s[i0] = make_float2(m00.x * aa.x - m00.y * aa.y + m01.x * bb.x - m01.y * bb.y,
                            m00.x * aa.y + m00.y * aa.x + m01.x * bb.y + m01.y * bb.x);
        s[i1] = make_float2(m10.x * aa.x - m10.y * aa.y + m11.x * bb.x - m11.y * bb.y,
                            m10.x * aa.y + m10.y * aa.x + m11.x * bb.y + m11.y * bb.x);
    }
}

__global__ __launch_bounds__(256) void quantum_kernel(
    const float* __restrict__ ang, const float* __restrict__ theta0,
    const float* __restrict__ theta_rz, const float* __restrict__ theta_ps,
    const float* __restrict__ rot_p, float* __restrict__ out)
{
    __shared__ float2 s[1024];
    __shared__ float red[40];
    __shared__ float P[64];
    int b = blockIdx.x;
    int tid = threadIdx.x;

    // parallel per-block param prep: threads 0..12 each build one group in LDS
    if (tid < 13) {
        if (tid < 10) {
            int k = tid;
            float ak = ang[b * 10 + k];
            float th = theta0[k] + ak;
            if (k == 1) th += ak;                       // RxAll applies a[1] twice
            if (k == 5) th -= 0.78539816339745f;        // fixed RX(-pi/4)
            float c, sn; sincosf(0.5f * th, &sn, &c);
            float2 v0 = make_float2(c, 0.f), v1 = make_float2(0.f, -sn);
            if (k == 0) v1 = make_float2(-sn, 0.f);     // fold -i phase (CZ*CNOT*CY collapse)
            if (k == 2) { float ca, sa; sincosf(0.5f * ak, &sa, &ca);
                float2 n0 = make_float2(ca * v0.x - sa * v1.x, ca * v0.y - sa * v1.y);
                float2 n1 = make_float2(sa * v0.x + ca * v1.x, sa * v0.y + ca * v1.y);
                v0 = n0; v1 = n1; }                     // RY(a2)
            if (k == 3) { float ca, sa; sincosf(0.5f * ak, &sa, &ca);
                v0 = cmul(v0, make_float2(ca, -sa));
                v1 = cmul(v1, make_float2(ca, sa)); }   // RZ(a3)
            if (k == 4) { float2 t = v1; v1 = make_float2(-t.y, t.x); }            // S
            if (k == 5) { const float r = 0.70710678118655f;
                float2 t = v1; v1 = make_float2(r * (t.x - t.y), r * (t.x + t.y)); } // T
            if (k == 6) { float ca, sa; sincosf(0.5f * theta_rz[0], &sa, &ca);
                v0 = cmul(v0, make_float2(ca, -sa));
                v1 = cmul(v1, make_float2(ca, sa)); }   // RZ(theta_rz)
            if (k == 7) { float2 p = v0, q = v1;
                v0 = make_float2(0.5f * ((p.x - p.y) + (q.x + q.y)),
                                 0.5f * ((p.x + p.y) + (q.y - q.x)));
                v1 = make_float2(0.5f * ((p.x + p.y) + (q.x - q.y)),
                                 0.5f * ((p.y - p.x) + (q.x + q.y)));               // SX
                float c2, s2; sincosf(ak, &s2, &c2);
                v1 = cmul(v1, make_float2(c2, s2)); }   // fold Phase(a7)
            P[k * 4 + 0] = v0.x; P[k * 4 + 1] = v0.y;
            P[k * 4 + 2] = v1.x; P[k * 4 + 3] = v1.y;
        } else if (tid == 10) {
            float c1, s1; sincosf(theta_ps[0], &s1, &c1);
            P[40] = c1; P[41] = s1;
        } else if (tid == 11) {
            float c, sn; sincosf(0.5f * rot_p[1], &sn, &c);
            float A = 0.5f * (rot_p[0] + rot_p[2]), Bv = 0.5f * (rot_p[0] - rot_p[2]);
            float cA, sA; sincosf(A, &sA, &cA);
            float cB, sB; sincosf(Bv, &sB, &cB);
            P[44] = cA * c;  P[45] = -sA * c;
            P[46] = -cB * sn; P[47] = -sB * sn;
            P[48] = cB * sn;  P[49] = -sB * sn;
            P[50] = cA * c;  P[51] = sA * c;
        } else {
            float a6 = ang[b * 10 + 6], a7 = ang[b * 10 + 7], a8 = ang[b * 10 + 8];
            float c, sn; sincosf(0.5f * a7, &sn, &c);
            float A = 0.5f * (a6 + a8), Bv = 0.5f * (a6 - a8);
            float cA, sA; sincosf(A, &sA, &cA);
            float cB, sB; sincosf(Bv, &sB, &cB);
            P[52] = cA * c;  P[53] = -sA * c;
            P[54] = -cB * sn; P[55] = -sB * sn;
            P[56] = cB * sn;  P[57] = -sB * sn;
            P[58] = cA * c;  P[59] = sA * c;
        }
    }
    __syncthreads();

    // load per-wire states; slots 2/3 exchanged (SWAP(2,3) pushed into init)
    float2 v[10][2];
#pragma unroll
    for (int k = 0; k < 10; ++k) {
        int slot = (k == 2) ? 3 : (k == 3) ? 2 : k;
        v[k][0] = make_float2(P[slot * 4], P[slot * 4 + 1]);
        v[k][1] = make_float2(P[slot * 4 + 2], P[slot * 4 + 3]);
    }

    // product state init — compile-time indices only (no scratch, r9-proven)
    for (int i = tid; i < 1024; i += 256) {
        float2 c = ((i >> 9) & 1) ? v[0][1] : v[0][0];
#pragma unroll
        for (int k = 1; k < 10; ++k) {
            float2 vk = ((i >> (9 - k)) & 1) ? v[k][1] : v[k][0];
            c = cmul(c, vk);
        }
        s[i] = c;
    }
    __syncthreads();

    { // pass A: CY(ctrl bit7, tgt bit1) + Phase(theta_ps) on bit1 (disjoint writes)
        int j = tid;
        float2 p1 = make_float2(P[40], P[41]);
        int i0 = (j & 1) | (((j >> 1) & 31) << 2) | (((j >> 6) & 3) << 8) | 128;
        int i1 = i0 | 2;
        float2 t0 = s[i0], t1 = s[i1];
        s[i0] = make_float2(t1.y, -t1.x);                 // -i * s1
        s[i1] = cmul(make_float2(-t0.y, t0.x), p1);       //  i * s0, then phase
        int i2 = (j & 1) | 2 | (((j >> 1) & 31) << 2) | (((j >> 6) & 3) << 8); // bit7=0,bit1=1
        s[i2] = cmul(s[i2], p1);
    }
    __syncthreads();
    if (tid < 128) { // CSWAP(4,5,6): ctrl bit5, swap bits 4,3
        int j = tid;
        int i0 = (j & 7) | 16 | 32 | (((j >> 3) & 15) << 6);
        int i1 = i0 ^ 0x18;
        float2 t0 = s[i0], t1 = s[i1];
        s[i0] = t1; s[i1] = t0;
    }
    __syncthreads();
    if (tid < 128) { // TOFF(8,5,0): ctrl bits 1,4, tgt bit9
        int j = tid;
        int i0 = (j & 1) | 2 | (((j >> 1) & 3) << 2) | 16 | (((j >> 3) & 15) << 5);
        int i1 = i0 | 512;
        float2 t0 = s[i0], t1 = s[i1];
        s[i0] = t1; s[i1] = t0;
    }
    __syncthreads();
    apply_rot2(s, 5, make_float2(P[44], P[45]), make_float2(P[46], P[47]),
               make_float2(P[48], P[49]), make_float2(P[50], P[51]), tid);
    __syncthreads();
    apply_rot2(s, 4, make_float2(P[52], P[53]), make_float2(P[54], P[55]),
               make_float2(P[56], P[57]), make_float2(P[58], P[59]), tid);
    __syncthreads();

    int wave = tid >> 6;
    for (int k = 0; k < 10; ++k) {
        int p = 9 - k;
        float part = 0.f;
        for (int q = tid; q < 512; q += 256) {
            int i0 = ((q >> p) << (p + 1)) | (q & ((1 << p) - 1));
            int i1 = i0 | (1 << p);
            float2 aa = s[i0], bb = s[i1];
            part += aa.x * bb.y - aa.y * bb.x;
        }
        part *= 2.f;
#pragma unroll
        for (int off = 32; off > 0; off >>= 1)
            part += __shfl_down(part, off, 64);
        if ((tid & 63) == 0) red[k * 4 + wave] = part;
    }
    __syncthreads();
    if (tid == 0) {
        float ev[10];
        float mx = -1e30f;
#pragma unroll
        for (int k = 0; k < 10; ++k) {
            ev[k] = red[k * 4] + red[k * 4 + 1] + red[k * 4 + 2] + red[k * 4 + 3];
            mx = fmaxf(mx, ev[k]);
        }
        float sum = 0.f;
#pragma unroll
        for (int k = 0; k < 10; ++k) sum += expf(ev[k] - mx);
        float lse = mx + logf(sum);
#pragma unroll
        for (int k = 0; k < 10; ++k) out[b * 10 + k] = ev[k] - lse;
    }
}

extern "C" void kernel_launch(void* const* d_in, const int* in_sizes, int n_in,
                              void* d_out, int out_size, void* d_ws, size_t ws_size,
                              hipStream_t stream)
{
    (void)in_sizes; (void)n_in; (void)out_size; (void)ws_size;
    const float* x    = (const float*)d_in[0];
    const float* c1w  = (const float*)d_in[1];
    const float* c1b  = (const float*)d_in[2];
    const float* c2w  = (const float*)d_in[3];
    const float* c2b  = (const float*)d_in[4];
    const float* f1w  = (const float*)d_in[5];
    const float* f1b  = (const float*)d_in[6];
    const float* f2w  = (const float*)d_in[7];
    const float* f2b  = (const float*)d_in[8];
    const float* th0  = (const float*)d_in[9];
    const float* trz  = (const float*)d_in[10];
    const float* tps  = (const float*)d_in[11];
    const float* rotp = (const float*)d_in[12];
    float* out = (float*)d_out;

    char* ws = (char*)d_ws;
    ushort* h1b    = (ushort*)(ws);                       // 88,604,672 B
    ushort* pooled = (ushort*)(ws + 88604672);            // 37,748,736 B
    ushort* wt2    = (ushort*)(ws + 126353408);           //     36,864 B
    ushort* wf1    = (ushort*)(ws + 126390272);           //  2,359,296 B
    float*  part   = (float*)(ws + 128749568);            //  4,194,304 B
    float*  fc1o   = (float*)(ws + 132943872);            //  1,048,576 B
    float*  ang    = (float*)(ws + 133992448);            //     81,920 B

    prep_kernel<<<4680, 256, 0, stream>>>(c2w, f1w, wt2, wf1);
    conv1_kernel<<<21632, 256, 0, stream>>>(x, c1w, c1b, h1b);
    conv2_persist<<<256, 384, 0, stream>>>(h1b, wt2, c2b, pooled);
    fc1_mfma<<<dim3(64, 4), 256, 0, stream>>>(pooled, wf1, part);
    fc1_reduce_kernel<<<1024, 256, 0, stream>>>(part, f1b, fc1o);
    fc2_kernel<<<80, 256, 0, stream>>>(fc1o, f2w, f2b, ang);
    quantum_kernel<<<2048, 256, 0, stream>>>(ang, th0, trz, tps, rotp, out);
}